// Round 11
// baseline (139.809 us; speedup 1.0000x reference)
//
#include <hip/hip_runtime.h>
#include <hip/hip_bf16.h>

#define NPTS 131072
#define K 27
#define CIN 64
#define COUT 128
#define BM 128                // rows per conv block (8 waves: 4r x 2c)
#define NPAIR 14              // ceil(27/2) k-offset pairs per block

constexpr float BN_EPS = 1e-5f;
constexpr float NEG_SLOPE = 0.01f;

typedef __attribute__((ext_vector_type(8))) short short8;
typedef __attribute__((ext_vector_type(4))) float f32x4;

__device__ inline unsigned int pk_bf16(float a, float b) {
    __hip_bfloat16 ha = __float2bfloat16(a), hb = __float2bfloat16(b);
    unsigned short ua = *reinterpret_cast<unsigned short*>(&ha);
    unsigned short ub = *reinterpret_cast<unsigned short*>(&hb);
    return (unsigned int)ua | ((unsigned int)ub << 16);
}
__device__ inline unsigned short bf16_bits(float a) {
    __hip_bfloat16 h = __float2bfloat16(a);
    return *reinterpret_cast<unsigned short*>(&h);
}

// ---------------------------------------------------------------------------
// prep_all: fused prep_f + prep_w + prep_idx (one launch).
// ---------------------------------------------------------------------------
__global__ __launch_bounds__(256) void prep_all(
    const float* __restrict__ feats, const float* __restrict__ W,
    const int* __restrict__ nidx, const int* __restrict__ nmask,
    unsigned short* __restrict__ featsb, unsigned short* __restrict__ Wt,
    int* __restrict__ midx, int do_midx)
{
    size_t t = (size_t)blockIdx.x * 256 + threadIdx.x;   // 4096 blocks

    // feats -> bf16
    {
        const float4* src = (const float4*)(feats) + t * 2;
        float4 v0 = src[0], v1 = src[1];
        uint4 o;
        o.x = pk_bf16(v0.x, v0.y); o.y = pk_bf16(v0.z, v0.w);
        o.z = pk_bf16(v1.x, v1.y); o.w = pk_bf16(v1.z, v1.w);
        ((uint4*)featsb)[t] = o;
    }
    // W -> Wt (transposed)
    if (t < (size_t)K * COUT * CIN) {
        int k  = (int)(t / (COUT * CIN));
        int r  = (int)(t % (COUT * CIN));
        int co = r / CIN;
        int ci = r % CIN;
        Wt[t] = bf16_bits(W[(k * CIN + ci) * COUT + co]);
    }
    // mask fold -> midx (int4)
    if (do_midx && t < (size_t)(NPTS * K / 4)) {
        int4 iv = ((const int4*)nidx)[t];
        int4 mv = ((const int4*)nmask)[t];
        int4 o;
        o.x = mv.x ? iv.x : NPTS;
        o.y = mv.y ? iv.y : NPTS;
        o.z = mv.z ? iv.z : NPTS;
        o.w = mv.w ? iv.w : NPTS;
        ((int4*)midx)[t] = o;
    }
}

// ---------------------------------------------------------------------------
// conv: R10 structure with PAIRED k-offsets (BK=2).  14 barrier-coupled
// iterations instead of 27: each stages A,B for k=2q and 2q+1 (64 KB LDS),
// then runs 32 MFMA/wave.  Prefetch cover and barrier amortization double.
// Odd K handled via sentinel-zero A row for the phantom k=27.
// ---------------------------------------------------------------------------
template<bool MIDX, bool YB>
__global__ __launch_bounds__(512) void conv_kernel(
    const unsigned short* __restrict__ featsb,   // (NPTS+1) rows, last = 0
    const int* __restrict__ midx,                // if MIDX
    const int* __restrict__ nidx,                // else
    const int* __restrict__ nmask,
    const unsigned short* __restrict__ Wt,       // [27][128][64] bf16
    float* __restrict__ y,                       // if !YB
    unsigned short* __restrict__ ybf,            // if YB
    float* __restrict__ accum)                   // [256]: sums then sumsqs
{
    __shared__ unsigned char Abuf[2][BM * 128];      // 2 x 16 KB
    __shared__ unsigned char Bbuf[2][COUT * 128];    // 2 x 16 KB (64 KB total)

    const int tid  = threadIdx.x;
    const int l    = tid & 63;
    const int wid  = tid >> 6;        // 0..7
    const int wr   = wid >> 1;        // 0..3 (32 rows each)
    const int wc   = wid & 1;         // 0..1 (64 cols each)
    const int base = blockIdx.x * BM;

    const int arow = tid >> 2;        // 4 thr/row, 32 B each
    const int aq   = tid & 3;
    const int bcol = tid >> 2;        // 4 thr/col, 32 B each
    const int bq   = tid & 3;

    auto loadIdx = [&](int kq) -> int {
        if (kq >= K) return NPTS;     // phantom offset -> sentinel zero row
        int o = (base + arow) * K + kq;
        if constexpr (MIDX) return midx[o];
        else                return nmask[o] ? nidx[o] : NPTS;
    };

    const int aswz = (arow & 7) << 4;
    const int aoff = arow * 128;
    const int bswz = (bcol & 7) << 4;
    const int boff = bcol * 128;

    uint4 a00, a01, a10, a11;         // staged A: pair-even, pair-odd
    uint4 b00, b01, b10, b11;         // staged B: pair-even, pair-odd
    int   idE, idO;

#define ISSUE_A2(i0, i1)                                                      \
    { const uint4* p0_ = (const uint4*)(featsb + (size_t)(i0) * CIN) + aq * 2;\
      a00 = p0_[0]; a01 = p0_[1];                                             \
      const uint4* p1_ = (const uint4*)(featsb + (size_t)(i1) * CIN) + aq * 2;\
      a10 = p1_[0]; a11 = p1_[1]; }
#define ISSUE_B2(q)                                                           \
    { int k0_ = 2 * (q);     if (k0_ > K - 1) k0_ = K - 1;                    \
      int k1_ = 2 * (q) + 1; if (k1_ > K - 1) k1_ = K - 1;                    \
      const uint4* p0_ = (const uint4*)(Wt + ((size_t)k0_ * COUT + bcol) * CIN) + bq * 2; \
      b00 = p0_[0]; b01 = p0_[1];                                             \
      const uint4* p1_ = (const uint4*)(Wt + ((size_t)k1_ * COUT + bcol) * CIN) + bq * 2; \
      b10 = p1_[0]; b11 = p1_[1]; }
#define WRITE_AB2()                                                           \
    { *(uint4*)(&Abuf[0][aoff + ((aq * 32 +  0) ^ aswz)]) = a00;              \
      *(uint4*)(&Abuf[0][aoff + ((aq * 32 + 16) ^ aswz)]) = a01;              \
      *(uint4*)(&Abuf[1][aoff + ((aq * 32 +  0) ^ aswz)]) = a10;              \
      *(uint4*)(&Abuf[1][aoff + ((aq * 32 + 16) ^ aswz)]) = a11;              \
      *(uint4*)(&Bbuf[0][boff + ((bq * 32 +  0) ^ bswz)]) = b00;              \
      *(uint4*)(&Bbuf[0][boff + ((bq * 32 + 16) ^ bswz)]) = b01;              \
      *(uint4*)(&Bbuf[1][boff + ((bq * 32 +  0) ^ bswz)]) = b10;              \
      *(uint4*)(&Bbuf[1][boff + ((bq * 32 + 16) ^ bswz)]) = b11; }

    f32x4 acc[2][4];
#pragma unroll
    for (int m = 0; m < 2; ++m)
#pragma unroll
        for (int n = 0; n < 4; ++n) acc[m][n] = (f32x4)0.f;

#define MFMA_TILE(PO)                                                         \
    _Pragma("unroll")                                                         \
    for (int ks = 0; ks < 2; ++ks) {                                          \
        const int kbyte = ks * 64 + (l >> 4) * 16;                            \
        short8 afr[2], bfr[4];                                                \
        _Pragma("unroll")                                                     \
        for (int m = 0; m < 2; ++m) {                                         \
            int row = wr * 32 + m * 16 + (l & 15);                            \
            afr[m] = *(const short8*)(&Abuf[PO][row * 128                     \
                        + (kbyte ^ ((row & 7) << 4))]);                       \
        }                                                                     \
        _Pragma("unroll")                                                     \
        for (int n = 0; n < 4; ++n) {                                         \
            int col = wc * 64 + n * 16 + (l & 15);                            \
            bfr[n] = *(const short8*)(&Bbuf[PO][col * 128                     \
                        + (kbyte ^ ((col & 7) << 4))]);                       \
        }                                                                     \
        _Pragma("unroll")                                                     \
        for (int m = 0; m < 2; ++m)                                           \
            _Pragma("unroll")                                                 \
            for (int n = 0; n < 4; ++n)                                       \
                acc[m][n] = __builtin_amdgcn_mfma_f32_16x16x32_bf16(          \
                    afr[m], bfr[n], acc[m][n], 0, 0, 0);                      \
    }

    // ---- prologue: pair 0 staged; ids for pair 1 prefetched ----
    {
        int i0 = loadIdx(0), i1 = loadIdx(1);
        ISSUE_A2(i0, i1);
        ISSUE_B2(0);
        idE = loadIdx(2); idO = loadIdx(3);
    }

    // ---- main loop: 14 pair-iterations, 2 barriers each ----
    for (int q = 0; q < NPAIR; ++q) {
        __syncthreads();              // waves done reading pair q-1
        WRITE_AB2();
        if (q + 1 < NPAIR) {
            ISSUE_A2(idE, idO);       // pair q+1: flies across MFMA phase
            ISSUE_B2(q + 1);
            idE = loadIdx(2 * q + 4); idO = loadIdx(2 * q + 5);
        }
        __syncthreads();              // pair q visible
        MFMA_TILE(0);
        MFMA_TILE(1);
    }

    // ---- y write: C/D layout col=l&15, row=(l>>4)*4+r ----
#pragma unroll
    for (int m = 0; m < 2; ++m)
#pragma unroll
        for (int n = 0; n < 4; ++n) {
            int gcol = wc * 64 + n * 16 + (l & 15);
#pragma unroll
            for (int r = 0; r < 4; ++r) {
                int grow = base + wr * 32 + m * 16 + (l >> 4) * 4 + r;
                if constexpr (YB) {
                    __builtin_nontemporal_store(bf16_bits(acc[m][n][r]),
                        &ybf[(size_t)grow * COUT + gcol]);
                } else {
                    __builtin_nontemporal_store(acc[m][n][r],
                        &y[(size_t)grow * COUT + gcol]);
                }
            }
        }

    // ---- fused per-block BN stats (exact f32, from acc regs) ----
    float sv[4], s2v[4];
#pragma unroll
    for (int n = 0; n < 4; ++n) {
        float s = 0.f, s2 = 0.f;
#pragma unroll
        for (int m = 0; m < 2; ++m)
#pragma unroll
            for (int r = 0; r < 4; ++r) { float v = acc[m][n][r]; s += v; s2 += v * v; }
        s  += __shfl_xor(s, 16);  s  += __shfl_xor(s, 32);
        s2 += __shfl_xor(s2, 16); s2 += __shfl_xor(s2, 32);
        sv[n] = s; s2v[n] = s2;
    }
    __syncthreads();                  // all MFMA reads of Abuf done
    float* statf = (float*)Abuf[0];   // [2][4][128] f32 = 4 KB
    if (l < 16) {
#pragma unroll
        for (int n = 0; n < 4; ++n) {
            int c = wc * 64 + n * 16 + l;
            statf[(0 * 4 + wr) * 128 + c] = sv[n];
            statf[(1 * 4 + wr) * 128 + c] = s2v[n];
        }
    }
    __syncthreads();
    if (tid < 128) {
        float s  = statf[0 * 128 + tid] + statf[1 * 128 + tid]
                 + statf[2 * 128 + tid] + statf[3 * 128 + tid];
        float s2 = statf[4 * 128 + tid] + statf[5 * 128 + tid]
                 + statf[6 * 128 + tid] + statf[7 * 128 + tid];
        atomicAdd(&accum[tid], s);
        atomicAdd(&accum[128 + tid], s2);
    }
#undef ISSUE_A2
#undef ISSUE_B2
#undef WRITE_AB2
#undef MFMA_TILE
}

// ---------------------------------------------------------------------------
// finalize: fold mean/var/gamma/beta into per-channel scale+bias
// ---------------------------------------------------------------------------
__global__ void finalize_kernel(const float* __restrict__ accum,
                                const float* __restrict__ gamma,
                                const float* __restrict__ beta,
                                float* __restrict__ sb)
{
    int c = threadIdx.x;                      // 128 threads
    float invN  = 1.0f / (float)NPTS;
    float mean  = accum[c] * invN;
    float var   = accum[128 + c] * invN - mean * mean;
    float scale = gamma[c] * rsqrtf(var + BN_EPS);
    sb[c]       = scale;
    sb[128 + c] = beta[c] - mean * scale;
}

// ---------------------------------------------------------------------------
// bn: out = leaky(y*scale+bias).  YB: read bf16 y (8 ch / thread, uint4).
// ---------------------------------------------------------------------------
template<bool YB>
__global__ __launch_bounds__(256) void bn_kernel(
    const unsigned short* __restrict__ ybf, float* __restrict__ y,
    const float* __restrict__ sb)
{
    size_t start = (size_t)blockIdx.x * blockDim.x + threadIdx.x;
    const size_t step = (size_t)gridDim.x * blockDim.x;
    if constexpr (YB) {
        int c0 = (int)((start * 8) & (COUT - 1));   // grid-stride invariant
        float sc[8], bi[8];
#pragma unroll
        for (int j = 0; j < 8; ++j) { sc[j] = sb[c0 + j]; bi[j] = sb[COUT + c0 + j]; }
        const size_t total = (size_t)NPTS * COUT / 8;
        for (size_t idx = start; idx < total; idx += step) {
            uint4 u = ((const uint4*)ybf)[idx];
            unsigned int uu[4] = {u.x, u.y, u.z, u.w};
            float o[8];
#pragma unroll
            for (int j = 0; j < 4; ++j) {
                float vlo = __uint_as_float(uu[j] << 16);
                float vhi = __uint_as_float(uu[j] & 0xffff0000u);
                float a = vlo * sc[2*j]   + bi[2*j];
                float b = vhi * sc[2*j+1] + bi[2*j+1];
                o[2*j]   = a > 0.f ? a : NEG_SLOPE * a;
                o[2*j+1] = b > 0.f ? b : NEG_SLOPE * b;
            }
            float4* dst = (float4*)(y + idx * 8);
            dst[0] = make_float4(o[0], o[1], o[2], o[3]);
            dst[1] = make_float4(o[4], o[5], o[6], o[7]);
        }
    } else {
        int c0 = (int)((start * 4) & (COUT - 1));
        float sc[4], bi[4];
#pragma unroll
        for (int j = 0; j < 4; ++j) { sc[j] = sb[c0 + j]; bi[j] = sb[COUT + c0 + j]; }
        const size_t total = (size_t)NPTS * COUT / 4;
        for (size_t idx = start; idx < total; idx += step) {
            float4 v = ((const float4*)y)[idx];
            v.x = v.x * sc[0] + bi[0]; v.x = v.x > 0.f ? v.x : NEG_SLOPE * v.x;
            v.y = v.y * sc[1] + bi[1]; v.y = v.y > 0.f ? v.y : NEG_SLOPE * v.y;
            v.z = v.z * sc[2] + bi[2]; v.z = v.z > 0.f ? v.z : NEG_SLOPE * v.z;
            v.w = v.w * sc[3] + bi[3]; v.w = v.w > 0.f ? v.w : NEG_SLOPE * v.w;
            ((float4*)y)[idx] = v;
        }
    }
}

extern "C" void kernel_launch(void* const* d_in, const int* in_sizes, int n_in,
                              void* d_out, int out_size, void* d_ws, size_t ws_size,
                              hipStream_t stream)
{
    const float* feats = (const float*)d_in[0];
    const int*   nidx  = (const int*)d_in[1];
    const int*   nmask = (const int*)d_in[2];
    const float* W     = (const float*)d_in[3];
    const float* gamma = (const float*)d_in[4];
    const float* beta  = (const float*)d_in[5];

    float* y = (float*)d_out;

    // ws layout (byte offsets)
    float*          accum  = (float*)d_ws;                               // 1 KB
    float*          sb     = (float*)((char*)d_ws + 1024);               // 1 KB
    unsigned short* Wt     = (unsigned short*)((char*)d_ws + 4096);      // 442 KB
    unsigned short* featsb = (unsigned short*)((char*)d_ws + 458752);    // 16.78 MB
    int*            midx   = (int*)((char*)d_ws + 17236224);             // 14.16 MB
    unsigned short* ybf    = (unsigned short*)((char*)d_ws + 31494144);  // 33.55 MB
    const size_t need_midx = 31494144;
    const size_t need_ybf  = 31494144 + (size_t)NPTS * COUT * 2;
    const bool use_midx = ws_size >= need_midx;
    const bool use_ybf  = ws_size >= need_ybf;

    hipMemsetAsync(accum, 0, 2 * COUT * sizeof(float), stream);
    hipMemsetAsync(featsb + (size_t)NPTS * CIN, 0, CIN * 2, stream);   // sentinel

    prep_all<<<4096, 256, 0, stream>>>(feats, W, nidx, nmask,
                                       featsb, Wt, midx, (int)use_midx);

    if (use_midx && use_ybf)
        conv_kernel<true, true ><<<NPTS / BM, 512, 0, stream>>>(featsb, midx, nidx, nmask, Wt, y, ybf, accum);
    else if (use_midx)
        conv_kernel<true, false><<<NPTS / BM, 512, 0, stream>>>(featsb, midx, nidx, nmask, Wt, y, ybf, accum);
    else
        conv_kernel<false, false><<<NPTS / BM, 512, 0, stream>>>(featsb, midx, nidx, nmask, Wt, y, ybf, accum);

    finalize_kernel<<<1, 128, 0, stream>>>(accum, gamma, beta, sb);

    if (use_midx && use_ybf)
        bn_kernel<true ><<<2048, 256, 0, stream>>>(ybf, y, sb);
    else
        bn_kernel<false><<<2048, 256, 0, stream>>>(ybf, y, sb);
}

// Round 12
// 125.931 us; speedup vs baseline: 1.1102x; 1.1102x over previous
//
#include <hip/hip_runtime.h>
#include <hip/hip_bf16.h>
#include <hip/hip_cooperative_groups.h>

namespace cg = cooperative_groups;

#define NPTS 131072
#define K 27
#define CIN 64
#define COUT 128
#define BM 128                // rows per conv block (8 waves: 4r x 2c)

constexpr float BN_EPS = 1e-5f;
constexpr float NEG_SLOPE = 0.01f;

typedef __attribute__((ext_vector_type(8))) short short8;
typedef __attribute__((ext_vector_type(4))) float f32x4;

__device__ inline unsigned int pk_bf16(float a, float b) {
    __hip_bfloat16 ha = __float2bfloat16(a), hb = __float2bfloat16(b);
    unsigned short ua = *reinterpret_cast<unsigned short*>(&ha);
    unsigned short ub = *reinterpret_cast<unsigned short*>(&hb);
    return (unsigned int)ua | ((unsigned int)ub << 16);
}
__device__ inline unsigned short bf16_bits(float a) {
    __hip_bfloat16 h = __float2bfloat16(a);
    return *reinterpret_cast<unsigned short*>(&h);
}

// ---------------------------------------------------------------------------
// prep_all: fused feats->bf16, W transpose->bf16, mask-fold->midx
// ---------------------------------------------------------------------------
__global__ __launch_bounds__(256) void prep_all(
    const float* __restrict__ feats, const float* __restrict__ W,
    const int* __restrict__ nidx, const int* __restrict__ nmask,
    unsigned short* __restrict__ featsb, unsigned short* __restrict__ Wt,
    int* __restrict__ midx, int do_midx)
{
    size_t t = (size_t)blockIdx.x * 256 + threadIdx.x;   // 4096 blocks

    {
        const float4* src = (const float4*)(feats) + t * 2;
        float4 v0 = src[0], v1 = src[1];
        uint4 o;
        o.x = pk_bf16(v0.x, v0.y); o.y = pk_bf16(v0.z, v0.w);
        o.z = pk_bf16(v1.x, v1.y); o.w = pk_bf16(v1.z, v1.w);
        ((uint4*)featsb)[t] = o;
    }
    if (t < (size_t)K * COUT * CIN) {
        int k  = (int)(t / (COUT * CIN));
        int r  = (int)(t % (COUT * CIN));
        int co = r / CIN;
        int ci = r % CIN;
        Wt[t] = bf16_bits(W[(k * CIN + ci) * COUT + co]);
    }
    if (do_midx && t < (size_t)(NPTS * K / 4)) {
        int4 iv = ((const int4*)nidx)[t];
        int4 mv = ((const int4*)nmask)[t];
        int4 o;
        o.x = mv.x ? iv.x : NPTS;
        o.y = mv.y ? iv.y : NPTS;
        o.z = mv.z ? iv.z : NPTS;
        o.w = mv.w ? iv.w : NPTS;
        ((int4*)midx)[t] = o;
    }
}

// ===========================================================================
// Shared conv-loop body (R10-proven): emitted via macro into both the fused
// cooperative kernel and the fallback kernel.
// ===========================================================================
#define CONV_BODY_COMMON(LOADIDX_EXPR)                                        \
    __shared__ unsigned char Alds[BM * 128];      /* 16 KB */                 \
    __shared__ unsigned char Blds[COUT * 128];    /* 16 KB */                 \
    const int tid  = threadIdx.x;                                             \
    const int l    = tid & 63;                                                \
    const int wid  = tid >> 6;                                                \
    const int wr   = wid >> 1;                                                \
    const int wc   = wid & 1;                                                 \
    const int base = blockIdx.x * BM;                                         \
    const int arow = tid >> 2;                                                \
    const int aq   = tid & 3;                                                 \
    const int bcol = tid >> 2;                                                \
    const int bq   = tid & 3;                                                 \
    auto loadIdx = [&](int kq) -> int {                                       \
        kq = kq < K ? kq : K - 1;                                             \
        int o = (base + arow) * K + kq;                                       \
        return LOADIDX_EXPR;                                                  \
    };                                                                        \
    const int aswz = (arow & 7) << 4;                                         \
    unsigned char* ap = Alds + arow * 128;                                    \
    const int bswz = (bcol & 7) << 4;                                         \
    unsigned char* bp = Blds + bcol * 128;                                    \
    uint4 a0, a1, b0, b1;                                                     \
    int   id_nxt;                                                             \
    f32x4 acc[2][4];                                                          \
    _Pragma("unroll")                                                         \
    for (int m = 0; m < 2; ++m)                                               \
        _Pragma("unroll")                                                     \
        for (int n = 0; n < 4; ++n) acc[m][n] = (f32x4)0.f;                   \
    {                                                                         \
        int id0 = loadIdx(0);                                                 \
        const uint4* pa = (const uint4*)(featsb + (size_t)id0 * CIN) + aq * 2;\
        a0 = pa[0]; a1 = pa[1];                                               \
        const uint4* pb = (const uint4*)(Wt + (size_t)bcol * CIN) + bq * 2;   \
        b0 = pb[0]; b1 = pb[1];                                               \
        id_nxt = loadIdx(1);                                                  \
    }                                                                         \
    for (int k = 0; k < K; ++k) {                                             \
        __syncthreads();                                                      \
        *(uint4*)(ap + ((aq * 32 +  0) ^ aswz)) = a0;                         \
        *(uint4*)(ap + ((aq * 32 + 16) ^ aswz)) = a1;                         \
        *(uint4*)(bp + ((bq * 32 +  0) ^ bswz)) = b0;                         \
        *(uint4*)(bp + ((bq * 32 + 16) ^ bswz)) = b1;                         \
        if (k + 1 < K) {                                                      \
            const uint4* pa = (const uint4*)(featsb + (size_t)id_nxt * CIN) + aq * 2; \
            a0 = pa[0]; a1 = pa[1];                                           \
            const uint4* pb = (const uint4*)(Wt + ((size_t)(k + 1) * COUT + bcol) * CIN) + bq * 2; \
            b0 = pb[0]; b1 = pb[1];                                           \
            id_nxt = loadIdx(k + 2);                                          \
        }                                                                     \
        __syncthreads();                                                      \
        _Pragma("unroll")                                                     \
        for (int ks = 0; ks < 2; ++ks) {                                      \
            const int kbyte = ks * 64 + (l >> 4) * 16;                        \
            short8 afr[2], bfr[4];                                            \
            _Pragma("unroll")                                                 \
            for (int m = 0; m < 2; ++m) {                                     \
                int row = wr * 32 + m * 16 + (l & 15);                        \
                afr[m] = *(const short8*)(Alds + row * 128                    \
                            + (kbyte ^ ((row & 7) << 4)));                    \
            }                                                                 \
            _Pragma("unroll")                                                 \
            for (int n = 0; n < 4; ++n) {                                     \
                int col = wc * 64 + n * 16 + (l & 15);                        \
                bfr[n] = *(const short8*)(Blds + col * 128                    \
                            + (kbyte ^ ((col & 7) << 4)));                    \
            }                                                                 \
            _Pragma("unroll")                                                 \
            for (int m = 0; m < 2; ++m)                                       \
                _Pragma("unroll")                                             \
                for (int n = 0; n < 4; ++n)                                   \
                    acc[m][n] = __builtin_amdgcn_mfma_f32_16x16x32_bf16(      \
                        afr[m], bfr[n], acc[m][n], 0, 0, 0);                  \
        }                                                                     \
    }                                                                         \
    /* per-block BN stats */                                                  \
    float sv[4], s2v[4];                                                      \
    _Pragma("unroll")                                                         \
    for (int n = 0; n < 4; ++n) {                                             \
        float s = 0.f, s2 = 0.f;                                              \
        _Pragma("unroll")                                                     \
        for (int m = 0; m < 2; ++m)                                           \
            _Pragma("unroll")                                                 \
            for (int r = 0; r < 4; ++r) { float v = acc[m][n][r]; s += v; s2 += v * v; } \
        s  += __shfl_xor(s, 16);  s  += __shfl_xor(s, 32);                    \
        s2 += __shfl_xor(s2, 16); s2 += __shfl_xor(s2, 32);                   \
        sv[n] = s; s2v[n] = s2;                                               \
    }                                                                         \
    __syncthreads();                                                          \
    float* statf = (float*)Alds;                                              \
    if (l < 16) {                                                             \
        _Pragma("unroll")                                                     \
        for (int n = 0; n < 4; ++n) {                                         \
            int c = wc * 64 + n * 16 + l;                                     \
            statf[(0 * 4 + wr) * 128 + c] = sv[n];                            \
            statf[(1 * 4 + wr) * 128 + c] = s2v[n];                           \
        }                                                                     \
    }                                                                         \
    __syncthreads();                                                          \
    if (tid < 128) {                                                          \
        float s  = statf[0 * 128 + tid] + statf[1 * 128 + tid]               \
                 + statf[2 * 128 + tid] + statf[3 * 128 + tid];              \
        float s2 = statf[4 * 128 + tid] + statf[5 * 128 + tid]               \
                 + statf[6 * 128 + tid] + statf[7 * 128 + tid];              \
        atomicAdd(&accum[tid], s);                                            \
        atomicAdd(&accum[128 + tid], s2);                                     \
    }

// ---------------------------------------------------------------------------
// FUSED cooperative conv: conv + stats + grid.sync + BN-apply + LeakyReLU.
// Exactly 1024 blocks x 512 thr = 4 blocks/CU (verified via occupancy query
// on the host before choosing this path).
// ---------------------------------------------------------------------------
__global__ __launch_bounds__(512, 8) void conv_fused(
    const unsigned short* __restrict__ featsb,
    const int* __restrict__ midx,
    const unsigned short* __restrict__ Wt,
    float* __restrict__ y,
    const float* __restrict__ gamma,
    const float* __restrict__ beta,
    float* accum)
{
    CONV_BODY_COMMON(midx[o])

    // ---- grid-wide sync: all blocks' stats visible ----
    cg::this_grid().sync();

    // ---- per-channel scale/bias (recomputed per block; L2-hot reads) ----
    float* sbuf = (float*)Blds;       // 1 KB
    if (tid < 128) {
        const volatile float* ac = (const volatile float*)accum;
        float invN  = 1.0f / (float)NPTS;
        float s     = ac[tid];
        float s2    = ac[128 + tid];
        float mean  = s * invN;
        float var   = s2 * invN - mean * mean;
        float scale = gamma[tid] * rsqrtf(var + BN_EPS);
        sbuf[tid]       = scale;
        sbuf[128 + tid] = beta[tid] - mean * scale;
    }
    __syncthreads();

    // ---- apply BN + LeakyReLU from registers, single f32 store ----
#pragma unroll
    for (int m = 0; m < 2; ++m)
#pragma unroll
        for (int n = 0; n < 4; ++n) {
            int gcol = wc * 64 + n * 16 + (l & 15);
            float sc = sbuf[gcol], bi = sbuf[128 + gcol];
#pragma unroll
            for (int r = 0; r < 4; ++r) {
                int grow = base + wr * 32 + m * 16 + (l >> 4) * 4 + r;
                float v = acc[m][n][r] * sc + bi;
                v = v > 0.f ? v : NEG_SLOPE * v;
                __builtin_nontemporal_store(v, &y[(size_t)grow * COUT + gcol]);
            }
        }
}

// ---------------------------------------------------------------------------
// Fallback conv (R10-proven): writes y bf16 (or f32), stats to accum.
// ---------------------------------------------------------------------------
template<bool MIDX, bool YB>
__global__ __launch_bounds__(512) void conv_kernel(
    const unsigned short* __restrict__ featsb,
    const int* __restrict__ midx,
    const int* __restrict__ nidx,
    const int* __restrict__ nmask,
    const unsigned short* __restrict__ Wt,
    float* __restrict__ y,
    unsigned short* __restrict__ ybf,
    float* accum)
{
    CONV_BODY_COMMON((MIDX ? midx[o] : (nmask[o] ? nidx[o] : NPTS)))

#pragma unroll
    for (int m = 0; m < 2; ++m)
#pragma unroll
        for (int n = 0; n < 4; ++n) {
            int gcol = wc * 64 + n * 16 + (l & 15);
#pragma unroll
            for (int r = 0; r < 4; ++r) {
                int grow = base + wr * 32 + m * 16 + (l >> 4) * 4 + r;
                if constexpr (YB) {
                    __builtin_nontemporal_store(bf16_bits(acc[m][n][r]),
                        &ybf[(size_t)grow * COUT + gcol]);
                } else {
                    __builtin_nontemporal_store(acc[m][n][r],
                        &y[(size_t)grow * COUT + gcol]);
                }
            }
        }
}

// ---------------------------------------------------------------------------
// finalize + bn (fallback path only)
// ---------------------------------------------------------------------------
__global__ void finalize_kernel(const float* __restrict__ accum,
                                const float* __restrict__ gamma,
                                const float* __restrict__ beta,
                                float* __restrict__ sb)
{
    int c = threadIdx.x;
    float invN  = 1.0f / (float)NPTS;
    float mean  = accum[c] * invN;
    float var   = accum[128 + c] * invN - mean * mean;
    float scale = gamma[c] * rsqrtf(var + BN_EPS);
    sb[c]       = scale;
    sb[128 + c] = beta[c] - mean * scale;
}

template<bool YB>
__global__ __launch_bounds__(256) void bn_kernel(
    const unsigned short* __restrict__ ybf, float* __restrict__ y,
    const float* __restrict__ sb)
{
    size_t start = (size_t)blockIdx.x * blockDim.x + threadIdx.x;
    const size_t step = (size_t)gridDim.x * blockDim.x;
    if constexpr (YB) {
        int c0 = (int)((start * 8) & (COUT - 1));
        float sc[8], bi[8];
#pragma unroll
        for (int j = 0; j < 8; ++j) { sc[j] = sb[c0 + j]; bi[j] = sb[COUT + c0 + j]; }
        const size_t total = (size_t)NPTS * COUT / 8;
        for (size_t idx = start; idx < total; idx += step) {
            uint4 u = ((const uint4*)ybf)[idx];
            unsigned int uu[4] = {u.x, u.y, u.z, u.w};
            float o[8];
#pragma unroll
            for (int j = 0; j < 4; ++j) {
                float vlo = __uint_as_float(uu[j] << 16);
                float vhi = __uint_as_float(uu[j] & 0xffff0000u);
                float a = vlo * sc[2*j]   + bi[2*j];
                float b = vhi * sc[2*j+1] + bi[2*j+1];
                o[2*j]   = a > 0.f ? a : NEG_SLOPE * a;
                o[2*j+1] = b > 0.f ? b : NEG_SLOPE * b;
            }
            float4* dst = (float4*)(y + idx * 8);
            dst[0] = make_float4(o[0], o[1], o[2], o[3]);
            dst[1] = make_float4(o[4], o[5], o[6], o[7]);
        }
    } else {
        int c0 = (int)((start * 4) & (COUT - 1));
        float sc[4], bi[4];
#pragma unroll
        for (int j = 0; j < 4; ++j) { sc[j] = sb[c0 + j]; bi[j] = sb[COUT + c0 + j]; }
        const size_t total = (size_t)NPTS * COUT / 4;
        for (size_t idx = start; idx < total; idx += step) {
            float4 v = ((const float4*)y)[idx];
            v.x = v.x * sc[0] + bi[0]; v.x = v.x > 0.f ? v.x : NEG_SLOPE * v.x;
            v.y = v.y * sc[1] + bi[1]; v.y = v.y > 0.f ? v.y : NEG_SLOPE * v.y;
            v.z = v.z * sc[2] + bi[2]; v.z = v.z > 0.f ? v.z : NEG_SLOPE * v.z;
            v.w = v.w * sc[3] + bi[3]; v.w = v.w > 0.f ? v.w : NEG_SLOPE * v.w;
            ((float4*)y)[idx] = v;
        }
    }
}

extern "C" void kernel_launch(void* const* d_in, const int* in_sizes, int n_in,
                              void* d_out, int out_size, void* d_ws, size_t ws_size,
                              hipStream_t stream)
{
    const float* feats = (const float*)d_in[0];
    const int*   nidx  = (const int*)d_in[1];
    const int*   nmask = (const int*)d_in[2];
    const float* W     = (const float*)d_in[3];
    const float* gamma = (const float*)d_in[4];
    const float* beta  = (const float*)d_in[5];

    float* y = (float*)d_out;

    // ws layout (byte offsets)
    float*          accum  = (float*)d_ws;                               // 1 KB
    float*          sb     = (float*)((char*)d_ws + 1024);               // 1 KB
    unsigned short* Wt     = (unsigned short*)((char*)d_ws + 4096);      // 442 KB
    unsigned short* featsb = (unsigned short*)((char*)d_ws + 458752);    // 16.78 MB
    int*            midx   = (int*)((char*)d_ws + 17236224);             // 14.16 MB
    unsigned short* ybf    = (unsigned short*)((char*)d_ws + 31494144);  // 33.55 MB
    const size_t need_midx = 31494144;
    const size_t need_ybf  = 31494144 + (size_t)NPTS * COUT * 2;
    const bool use_midx = ws_size >= need_midx;
    const bool use_ybf  = ws_size >= need_ybf;

    // coop path requires 4 co-resident blocks/CU for the 1024-block grid
    int maxb = 0;
    bool coop = use_midx;
    if (coop) {
        if (hipOccupancyMaxActiveBlocksPerMultiprocessor(
                &maxb, conv_fused, 512, 0) != hipSuccess || maxb < 4)
            coop = false;
    }

    hipMemsetAsync(accum, 0, 2 * COUT * sizeof(float), stream);
    hipMemsetAsync(featsb + (size_t)NPTS * CIN, 0, CIN * 2, stream);   // sentinel

    prep_all<<<4096, 256, 0, stream>>>(feats, W, nidx, nmask,
                                       featsb, Wt, midx, (int)use_midx);

    if (coop) {
        void* args[] = {(void*)&featsb, (void*)&midx, (void*)&Wt, (void*)&y,
                        (void*)&gamma, (void*)&beta, (void*)&accum};
        hipLaunchCooperativeKernel((const void*)conv_fused,
                                   dim3(NPTS / BM), dim3(512), args, 0, stream);
        return;
    }

    // ---- fallback: R10-proven 4-kernel pipeline ----
    if (use_midx && use_ybf)
        conv_kernel<true, true ><<<NPTS / BM, 512, 0, stream>>>(featsb, midx, nidx, nmask, Wt, y, ybf, accum);
    else if (use_midx)
        conv_kernel<true, false><<<NPTS / BM, 512, 0, stream>>>(featsb, midx, nidx, nmask, Wt, y, ybf, accum);
    else
        conv_kernel<false, false><<<NPTS / BM, 512, 0, stream>>>(featsb, midx, nidx, nmask, Wt, y, ybf, accum);

    finalize_kernel<<<1, 128, 0, stream>>>(accum, gamma, beta, sb);

    if (use_midx && use_ybf)
        bn_kernel<true ><<<2048, 256, 0, stream>>>(ybf, y, sb);
    else
        bn_kernel<false><<<2048, 256, 0, stream>>>(ybf, y, sb);
}

// Round 13
// 114.354 us; speedup vs baseline: 1.2226x; 1.1012x over previous
//
#include <hip/hip_runtime.h>
#include <hip/hip_bf16.h>

#define NPTS 131072
#define K 27
#define CIN 64
#define COUT 128
#define BM 128                // rows per conv block (8 waves: 4r x 2c)

constexpr float BN_EPS = 1e-5f;
constexpr float NEG_SLOPE = 0.01f;

typedef __attribute__((ext_vector_type(8))) short short8;
typedef __attribute__((ext_vector_type(4))) float f32x4;

__device__ inline unsigned int pk_bf16(float a, float b) {
    __hip_bfloat16 ha = __float2bfloat16(a), hb = __float2bfloat16(b);
    unsigned short ua = *reinterpret_cast<unsigned short*>(&ha);
    unsigned short ub = *reinterpret_cast<unsigned short*>(&hb);
    return (unsigned int)ua | ((unsigned int)ub << 16);
}
__device__ inline unsigned short bf16_bits(float a) {
    __hip_bfloat16 h = __float2bfloat16(a);
    return *reinterpret_cast<unsigned short*>(&h);
}

// ---------------------------------------------------------------------------
// prep_all: feats->bf16, W transpose->bf16, mask-fold->midx, accum zero,
// sentinel-row zero.  Replaces 2 memsets + 3 prep kernels with ONE launch.
// ---------------------------------------------------------------------------
__global__ __launch_bounds__(256) void prep_all(
    const float* __restrict__ feats, const float* __restrict__ W,
    const int* __restrict__ nidx, const int* __restrict__ nmask,
    unsigned short* __restrict__ featsb, unsigned short* __restrict__ Wt,
    int* __restrict__ midx, float* __restrict__ accum, int do_midx)
{
    size_t t = (size_t)blockIdx.x * 256 + threadIdx.x;   // 4096 blocks

    // feats -> bf16 (32 B out / thread)
    {
        const float4* src = (const float4*)(feats) + t * 2;
        float4 v0 = src[0], v1 = src[1];
        uint4 o;
        o.x = pk_bf16(v0.x, v0.y); o.y = pk_bf16(v0.z, v0.w);
        o.z = pk_bf16(v1.x, v1.y); o.w = pk_bf16(v1.z, v1.w);
        ((uint4*)featsb)[t] = o;
    }
    // W -> Wt (transposed)
    if (t < (size_t)K * COUT * CIN) {
        int k  = (int)(t / (COUT * CIN));
        int r  = (int)(t % (COUT * CIN));
        int co = r / CIN;
        int ci = r % CIN;
        Wt[t] = bf16_bits(W[(k * CIN + ci) * COUT + co]);
    }
    // mask fold -> midx (int4)
    if (do_midx && t < (size_t)(NPTS * K / 4)) {
        int4 iv = ((const int4*)nidx)[t];
        int4 mv = ((const int4*)nmask)[t];
        int4 o;
        o.x = mv.x ? iv.x : NPTS;
        o.y = mv.y ? iv.y : NPTS;
        o.z = mv.z ? iv.z : NPTS;
        o.w = mv.w ? iv.w : NPTS;
        ((int4*)midx)[t] = o;
    }
    // accum zero (256 floats) + sentinel row zero (128 B)
    if (t < 2 * COUT) accum[t] = 0.f;
    if (t < 8) ((uint4*)(featsb + (size_t)NPTS * CIN))[t] = make_uint4(0,0,0,0);
}

// ---------------------------------------------------------------------------
// conv: R10-proven.  512 thr = 8 waves (4r x 2c), 128x128 tile, reg-staged
// gather -> XOR-swizzled LDS, 1-deep prefetch, 2 barriers/k, fused stats.
// ---------------------------------------------------------------------------
template<bool MIDX, bool YB>
__global__ __launch_bounds__(512) void conv_kernel(
    const unsigned short* __restrict__ featsb,   // (NPTS+1) rows, last = 0
    const int* __restrict__ midx,                // if MIDX
    const int* __restrict__ nidx,                // else
    const int* __restrict__ nmask,
    const unsigned short* __restrict__ Wt,       // [27][128][64] bf16
    float* __restrict__ y,                       // if !YB
    unsigned short* __restrict__ ybf,            // if YB
    float* __restrict__ accum)                   // [256]: sums then sumsqs
{
    __shared__ unsigned char Alds[BM * 128];      // 16 KB
    __shared__ unsigned char Blds[COUT * 128];    // 16 KB

    const int tid  = threadIdx.x;
    const int l    = tid & 63;
    const int wid  = tid >> 6;        // 0..7
    const int wr   = wid >> 1;        // 0..3 (32 rows each)
    const int wc   = wid & 1;         // 0..1 (64 cols each)
    const int base = blockIdx.x * BM;

    const int arow = tid >> 2;        // 4 thr/row, 32 B each
    const int aq   = tid & 3;
    const int bcol = tid >> 2;        // 4 thr/col, 32 B each
    const int bq   = tid & 3;

    auto loadIdx = [&](int kq) -> int {
        kq = kq < K ? kq : K - 1;     // clamp (redundant, harmless)
        int o = (base + arow) * K + kq;
        if constexpr (MIDX) return midx[o];
        else                return nmask[o] ? nidx[o] : NPTS;
    };

    const int aswz = (arow & 7) << 4;
    unsigned char* ap = Alds + arow * 128;
    const int bswz = (bcol & 7) << 4;
    unsigned char* bp = Blds + bcol * 128;

    uint4 a0, a1, b0, b1;             // staged regs (32 B A, 32 B B)
    int   id_nxt;

    f32x4 acc[2][4];
#pragma unroll
    for (int m = 0; m < 2; ++m)
#pragma unroll
        for (int n = 0; n < 4; ++n) acc[m][n] = (f32x4)0.f;

    // ---- prologue ----
    {
        int id0 = loadIdx(0);
        const uint4* pa = (const uint4*)(featsb + (size_t)id0 * CIN) + aq * 2;
        a0 = pa[0]; a1 = pa[1];
        const uint4* pb = (const uint4*)(Wt + (size_t)bcol * CIN) + bq * 2;
        b0 = pb[0]; b1 = pb[1];
        id_nxt = loadIdx(1);
    }

    // ---- main loop: 2 barriers per k ----
    for (int k = 0; k < K; ++k) {
        __syncthreads();              // waves done reading tile k-1
        *(uint4*)(ap + ((aq * 32 +  0) ^ aswz)) = a0;
        *(uint4*)(ap + ((aq * 32 + 16) ^ aswz)) = a1;
        *(uint4*)(bp + ((bq * 32 +  0) ^ bswz)) = b0;
        *(uint4*)(bp + ((bq * 32 + 16) ^ bswz)) = b1;
        if (k + 1 < K) {
            const uint4* pa = (const uint4*)(featsb + (size_t)id_nxt * CIN) + aq * 2;
            a0 = pa[0]; a1 = pa[1];
            const uint4* pb = (const uint4*)(Wt + ((size_t)(k + 1) * COUT + bcol) * CIN) + bq * 2;
            b0 = pb[0]; b1 = pb[1];
            id_nxt = loadIdx(k + 2);
        }
        __syncthreads();              // tile k visible
#pragma unroll
        for (int ks = 0; ks < 2; ++ks) {
            const int kbyte = ks * 64 + (l >> 4) * 16;
            short8 afr[2], bfr[4];
#pragma unroll
            for (int m = 0; m < 2; ++m) {
                int row = wr * 32 + m * 16 + (l & 15);
                afr[m] = *(const short8*)(Alds + row * 128
                            + (kbyte ^ ((row & 7) << 4)));
            }
#pragma unroll
            for (int n = 0; n < 4; ++n) {
                int col = wc * 64 + n * 16 + (l & 15);
                bfr[n] = *(const short8*)(Blds + col * 128
                            + (kbyte ^ ((col & 7) << 4)));
            }
#pragma unroll
            for (int m = 0; m < 2; ++m)
#pragma unroll
                for (int n = 0; n < 4; ++n)
                    acc[m][n] = __builtin_amdgcn_mfma_f32_16x16x32_bf16(
                        afr[m], bfr[n], acc[m][n], 0, 0, 0);
        }
    }

    // ---- y write: C/D layout col=l&15, row=(l>>4)*4+r ----
#pragma unroll
    for (int m = 0; m < 2; ++m)
#pragma unroll
        for (int n = 0; n < 4; ++n) {
            int gcol = wc * 64 + n * 16 + (l & 15);
#pragma unroll
            for (int r = 0; r < 4; ++r) {
                int grow = base + wr * 32 + m * 16 + (l >> 4) * 4 + r;
                if constexpr (YB) {
                    __builtin_nontemporal_store(bf16_bits(acc[m][n][r]),
                        &ybf[(size_t)grow * COUT + gcol]);
                } else {
                    __builtin_nontemporal_store(acc[m][n][r],
                        &y[(size_t)grow * COUT + gcol]);
                }
            }
        }

    // ---- fused per-block BN stats ----
    float sv[4], s2v[4];
#pragma unroll
    for (int n = 0; n < 4; ++n) {
        float s = 0.f, s2 = 0.f;
#pragma unroll
        for (int m = 0; m < 2; ++m)
#pragma unroll
            for (int r = 0; r < 4; ++r) { float v = acc[m][n][r]; s += v; s2 += v * v; }
        s  += __shfl_xor(s, 16);  s  += __shfl_xor(s, 32);
        s2 += __shfl_xor(s2, 16); s2 += __shfl_xor(s2, 32);
        sv[n] = s; s2v[n] = s2;
    }
    __syncthreads();                  // all MFMA reads of Alds done
    float* statf = (float*)Alds;      // [2][4][128] f32 = 4 KB
    if (l < 16) {
#pragma unroll
        for (int n = 0; n < 4; ++n) {
            int c = wc * 64 + n * 16 + l;
            statf[(0 * 4 + wr) * 128 + c] = sv[n];
            statf[(1 * 4 + wr) * 128 + c] = s2v[n];
        }
    }
    __syncthreads();
    if (tid < 128) {
        float s  = statf[0 * 128 + tid] + statf[1 * 128 + tid]
                 + statf[2 * 128 + tid] + statf[3 * 128 + tid];
        float s2 = statf[4 * 128 + tid] + statf[5 * 128 + tid]
                 + statf[6 * 128 + tid] + statf[7 * 128 + tid];
        atomicAdd(&accum[tid], s);
        atomicAdd(&accum[128 + tid], s2);
    }
}

// ---------------------------------------------------------------------------
// bn: in-block finalize (scale/bias from accum) + apply + LeakyReLU.
// ---------------------------------------------------------------------------
template<bool YB>
__global__ __launch_bounds__(256) void bn_kernel(
    const unsigned short* __restrict__ ybf, float* __restrict__ y,
    const float* __restrict__ accum,
    const float* __restrict__ gamma, const float* __restrict__ beta)
{
    __shared__ float sbuf[2][COUT];
    if (threadIdx.x < COUT) {
        int c = threadIdx.x;
        float invN  = 1.0f / (float)NPTS;
        float mean  = accum[c] * invN;
        float var   = accum[COUT + c] * invN - mean * mean;
        float scale = gamma[c] * rsqrtf(var + BN_EPS);
        sbuf[0][c] = scale;
        sbuf[1][c] = beta[c] - mean * scale;
    }
    __syncthreads();

    size_t start = (size_t)blockIdx.x * blockDim.x + threadIdx.x;
    const size_t step = (size_t)gridDim.x * blockDim.x;
    if constexpr (YB) {
        int c0 = (int)((start * 8) & (COUT - 1));   // grid-stride invariant
        float sc[8], bi[8];
#pragma unroll
        for (int j = 0; j < 8; ++j) { sc[j] = sbuf[0][c0 + j]; bi[j] = sbuf[1][c0 + j]; }
        const size_t total = (size_t)NPTS * COUT / 8;
        for (size_t idx = start; idx < total; idx += step) {
            uint4 u = ((const uint4*)ybf)[idx];
            unsigned int uu[4] = {u.x, u.y, u.z, u.w};
            float o[8];
#pragma unroll
            for (int j = 0; j < 4; ++j) {
                float vlo = __uint_as_float(uu[j] << 16);
                float vhi = __uint_as_float(uu[j] & 0xffff0000u);
                float a = vlo * sc[2*j]   + bi[2*j];
                float b = vhi * sc[2*j+1] + bi[2*j+1];
                o[2*j]   = a > 0.f ? a : NEG_SLOPE * a;
                o[2*j+1] = b > 0.f ? b : NEG_SLOPE * b;
            }
            float4* dst = (float4*)(y + idx * 8);
            dst[0] = make_float4(o[0], o[1], o[2], o[3]);
            dst[1] = make_float4(o[4], o[5], o[6], o[7]);
        }
    } else {
        int c0 = (int)((start * 4) & (COUT - 1));
        float sc[4], bi[4];
#pragma unroll
        for (int j = 0; j < 4; ++j) { sc[j] = sbuf[0][c0 + j]; bi[j] = sbuf[1][c0 + j]; }
        const size_t total = (size_t)NPTS * COUT / 4;
        for (size_t idx = start; idx < total; idx += step) {
            float4 v = ((const float4*)y)[idx];
            v.x = v.x * sc[0] + bi[0]; v.x = v.x > 0.f ? v.x : NEG_SLOPE * v.x;
            v.y = v.y * sc[1] + bi[1]; v.y = v.y > 0.f ? v.y : NEG_SLOPE * v.y;
            v.z = v.z * sc[2] + bi[2]; v.z = v.z > 0.f ? v.z : NEG_SLOPE * v.z;
            v.w = v.w * sc[3] + bi[3]; v.w = v.w > 0.f ? v.w : NEG_SLOPE * v.w;
            ((float4*)y)[idx] = v;
        }
    }
}

extern "C" void kernel_launch(void* const* d_in, const int* in_sizes, int n_in,
                              void* d_out, int out_size, void* d_ws, size_t ws_size,
                              hipStream_t stream)
{
    const float* feats = (const float*)d_in[0];
    const int*   nidx  = (const int*)d_in[1];
    const int*   nmask = (const int*)d_in[2];
    const float* W     = (const float*)d_in[3];
    const float* gamma = (const float*)d_in[4];
    const float* beta  = (const float*)d_in[5];

    float* y = (float*)d_out;

    // ws layout (byte offsets)
    float*          accum  = (float*)d_ws;                               // 1 KB
    unsigned short* Wt     = (unsigned short*)((char*)d_ws + 4096);      // 442 KB
    unsigned short* featsb = (unsigned short*)((char*)d_ws + 458752);    // 16.78 MB
    int*            midx   = (int*)((char*)d_ws + 17236224);             // 14.16 MB
    unsigned short* ybf    = (unsigned short*)((char*)d_ws + 31494144);  // 33.55 MB
    const size_t need_midx = 31494144;
    const size_t need_ybf  = 31494144 + (size_t)NPTS * COUT * 2;
    const bool use_midx = ws_size >= need_midx;
    const bool use_ybf  = ws_size >= need_ybf;

    prep_all<<<4096, 256, 0, stream>>>(feats, W, nidx, nmask,
                                       featsb, Wt, midx, accum, (int)use_midx);

    if (use_midx && use_ybf)
        conv_kernel<true, true ><<<NPTS / BM, 512, 0, stream>>>(featsb, midx, nidx, nmask, Wt, y, ybf, accum);
    else if (use_midx)
        conv_kernel<true, false><<<NPTS / BM, 512, 0, stream>>>(featsb, midx, nidx, nmask, Wt, y, ybf, accum);
    else
        conv_kernel<false, false><<<NPTS / BM, 512, 0, stream>>>(featsb, midx, nidx, nmask, Wt, y, ybf, accum);

    if (use_midx && use_ybf)
        bn_kernel<true ><<<2048, 256, 0, stream>>>(ybf, y, accum, gamma, beta);
    else
        bn_kernel<false><<<2048, 256, 0, stream>>>(ybf, y, accum, gamma, beta);
}